// Round 5
// baseline (385.172 us; speedup 1.0000x reference)
//
#include <hip/hip_runtime.h>
#include <hip/hip_bf16.h>

#define B_N 64
#define S_N 2048
#define E_N 512
#define A_N 512

typedef __bf16 bf16x8 __attribute__((ext_vector_type(8)));
typedef float  f32x4  __attribute__((ext_vector_type(4)));

__device__ __forceinline__ unsigned int f2bfu(float f) {
  return (unsigned int)__builtin_bit_cast(unsigned short, (__bf16)f);
}

// ------- K0a: pack W_enc fp32 [A][E] -> bf16 in MFMA-fragment order --------
// chunk pk = (c*16 + k32)*64 + l  (16 bytes each), l = q*16+ln
// holds W[a = c*16+ln][k = k32*32 + q*8 + j], j=0..7
__global__ __launch_bounds__(256) void k_pack(const float* __restrict__ W,
                                              unsigned short* __restrict__ Wp) {
  const int pk = blockIdx.x * 256 + threadIdx.x;      // [0, 32768)
  const int l = pk & 63, k32 = (pk >> 6) & 15, c = pk >> 10;
  const int ln = l & 15, q = l >> 4;
  const int a = c * 16 + ln, k = k32 * 32 + q * 8;
  const float* src = W + (size_t)a * E_N + k;
  const float4 u = *(const float4*)src;
  const float4 w = *(const float4*)(src + 4);
  uint4 o;
  o.x = f2bfu(u.x) | (f2bfu(u.y) << 16);
  o.y = f2bfu(u.z) | (f2bfu(u.w) << 16);
  o.z = f2bfu(w.x) | (f2bfu(w.y) << 16);
  o.w = f2bfu(w.z) | (f2bfu(w.w) << 16);
  *(uint4*)(Wp + (size_t)pk * 8) = o;
}

// ------- K0b: dec_proj[b][a] = dot(dec_hidden[b], W_dec[a]) ----------------
__global__ __launch_bounds__(256) void k_decproj(const float* __restrict__ dh,
                                                 const float* __restrict__ Wd,
                                                 float* __restrict__ decp) {
  const int b = blockIdx.x, tid = threadIdx.x;
  __shared__ float h[E_N];
  h[tid] = dh[b * E_N + tid];
  h[tid + 256] = dh[b * E_N + 256 + tid];
  __syncthreads();
  for (int a = tid; a < A_N; a += 256) {
    const float* wr = Wd + (size_t)a * E_N;
    float s = 0.f;
    #pragma unroll 8
    for (int e = 0; e < E_N; e += 4) {
      const float4 w4 = *(const float4*)(wr + e);
      s += w4.x * h[e] + w4.y * h[e + 1] + w4.z * h[e + 2] + w4.w * h[e + 3];
    }
    decp[b * A_N + a] = s;
  }
}

// ------- K1: partial scores, COMPACT CODE (rolled K-loop) -------------------
// Grid 4096: bid = (row-group g)*2 + col-half p. Block 256 thr = 4 waves.
// Block tile: 64 rows x 256 cols (cols p*256 + w*64 per wave).
// A: 64x64 bf16 LDS, double-buffered, register-pipelined staging.
// B: coalesced 1KB loads from packed Wp (L2-resident). 1 barrier/K-step.
#define LDS_ABUF 8192
#define RED_OFF  (2 * LDS_ABUF)
#define LDS_TOT  (2 * LDS_ABUF + 4 * 64 * 4)

__device__ __forceinline__ int a_off(int pb, int r, int kb) {
  return pb * LDS_ABUF + r * 128 + (kb ^ ((r & 7) << 4));
}

__global__ __launch_bounds__(256, 4) void k_scores(
    const float* __restrict__ enc, const unsigned short* __restrict__ Wp,
    const float* __restrict__ decp, const float* __restrict__ vvec,
    float* __restrict__ sp) {
  __shared__ __align__(16) unsigned char lds[LDS_TOT];
  const int tid = threadIdx.x;
  const int lane = tid & 63, w = tid >> 6, q = lane >> 4, ln = lane & 15;
  const int g = blockIdx.x >> 1, p = blockIdx.x & 1;
  const int m0 = g * 64;
  const int b = m0 >> 11;
  const bf16x8* __restrict__ Wp16 = (const bf16x8*)Wp;

  // epilogue constants
  float vv[4], dp[4];
  #pragma unroll
  for (int nt = 0; nt < 4; ++nt) {
    const int a = p * 256 + w * 64 + nt * 16 + ln;
    vv[nt] = vvec[a];
    dp[nt] = decp[b * A_N + a];
  }

  // staging map: thread -> row (tid>>2), 16-float chunk c4 (tid&3)
  const int srow = tid >> 2, c4 = tid & 3;
  const float* sbase = enc + (size_t)(m0 + srow) * E_N + c4 * 16;

  // prologue: stage ks=0 into buf 0
  {
    float4 L[4];
    #pragma unroll
    for (int j = 0; j < 4; ++j) L[j] = *(const float4*)(sbase + j * 4);
    #pragma unroll
    for (int h = 0; h < 2; ++h) {
      uint4 o;
      o.x = f2bfu(L[h*2].x)   | (f2bfu(L[h*2].y)   << 16);
      o.y = f2bfu(L[h*2].z)   | (f2bfu(L[h*2].w)   << 16);
      o.z = f2bfu(L[h*2+1].x) | (f2bfu(L[h*2+1].y) << 16);
      o.w = f2bfu(L[h*2+1].z) | (f2bfu(L[h*2+1].w) << 16);
      *(uint4*)(lds + a_off(0, srow, c4 * 32 + h * 16)) = o;
    }
  }
  __syncthreads();

  f32x4 acc[4][4] = {};

  #pragma unroll 1
  for (int ks = 0; ks < 8; ++ks) {
    const int pb = ks & 1;
    // issue next A-chunk loads early (retired at bottom of this iter)
    float4 L[4];
    if (ks < 7) {
      #pragma unroll
      for (int j = 0; j < 4; ++j)
        L[j] = *(const float4*)(sbase + (ks + 1) * 64 + j * 4);
    }
    // compute on buf pb
    #pragma unroll
    for (int kt = 0; kt < 2; ++kt) {
      bf16x8 bfr[4], afr[4];
      #pragma unroll
      for (int nt = 0; nt < 4; ++nt) {
        const int c = p * 16 + w * 4 + nt;
        bfr[nt] = Wp16[(size_t)(c * 16 + ks * 2 + kt) * 64 + lane];
      }
      #pragma unroll
      for (int mt = 0; mt < 4; ++mt)
        afr[mt] = *(const bf16x8*)(
            lds + a_off(pb, mt * 16 + ln, kt * 64 + q * 16));
      #pragma unroll
      for (int mt = 0; mt < 4; ++mt)
        #pragma unroll
        for (int nt = 0; nt < 4; ++nt)
          acc[mt][nt] = __builtin_amdgcn_mfma_f32_16x16x32_bf16(
              afr[mt], bfr[nt], acc[mt][nt], 0, 0, 0);
    }
    // retire staged loads into alternate buffer
    if (ks < 7) {
      #pragma unroll
      for (int h = 0; h < 2; ++h) {
        uint4 o;
        o.x = f2bfu(L[h*2].x)   | (f2bfu(L[h*2].y)   << 16);
        o.y = f2bfu(L[h*2].z)   | (f2bfu(L[h*2].w)   << 16);
        o.z = f2bfu(L[h*2+1].x) | (f2bfu(L[h*2+1].y) << 16);
        o.w = f2bfu(L[h*2+1].z) | (f2bfu(L[h*2+1].w) << 16);
        *(uint4*)(lds + a_off(pb ^ 1, srow, c4 * 32 + h * 16)) = o;
      }
    }
    __syncthreads();
  }

  // epilogue: tanh(x + decp) * v, reduce over this block's 256 cols
  float part[4][4] = {};
  #pragma unroll
  for (int mt = 0; mt < 4; ++mt)
    #pragma unroll
    for (int nt = 0; nt < 4; ++nt)
      #pragma unroll
      for (int r = 0; r < 4; ++r) {
        float x = acc[mt][nt][r] + dp[nt];
        x = fminf(9.f, fmaxf(-9.f, x));
        const float ex = __expf(2.f * x);
        part[mt][r] = fmaf(__fdividef(ex - 1.f, ex + 1.f), vv[nt], part[mt][r]);
      }
  float* red = (float*)(lds + RED_OFF);
  #pragma unroll
  for (int mt = 0; mt < 4; ++mt)
    #pragma unroll
    for (int r = 0; r < 4; ++r) {
      float s = part[mt][r];
      s += __shfl_xor(s, 1);
      s += __shfl_xor(s, 2);
      s += __shfl_xor(s, 4);
      s += __shfl_xor(s, 8);
      if (ln == 0) red[w * 64 + mt * 16 + q * 4 + r] = s;
    }
  __syncthreads();
  if (tid < 64) {
    const float s = red[tid] + red[64 + tid] + red[128 + tid] + red[192 + tid];
    sp[p * (B_N * S_N) + m0 + tid] = s;
  }
}

// ------- K2: softmax over S per b (sums the two col-half partials) ----------
__global__ __launch_bounds__(256) void k_softmax(const float* __restrict__ sp,
                                                 float* __restrict__ attn) {
  const int b = blockIdx.x, tid = threadIdx.x;
  float l[8];
  float mx = -3.4e38f;
  #pragma unroll
  for (int i = 0; i < 8; ++i) {
    const int idx = b * S_N + i * 256 + tid;
    l[i] = sp[idx] + sp[B_N * S_N + idx];
    mx = fmaxf(mx, l[i]);
  }
  #pragma unroll
  for (int m = 1; m < 64; m <<= 1) mx = fmaxf(mx, __shfl_xor(mx, m));
  __shared__ float sred[8];
  if ((tid & 63) == 0) sred[tid >> 6] = mx;
  __syncthreads();
  mx = fmaxf(fmaxf(sred[0], sred[1]), fmaxf(sred[2], sred[3]));
  float se = 0.f;
  #pragma unroll
  for (int i = 0; i < 8; ++i) { l[i] = __expf(l[i] - mx); se += l[i]; }
  #pragma unroll
  for (int m = 1; m < 64; m <<= 1) se += __shfl_xor(se, m);
  if ((tid & 63) == 0) sred[4 + (tid >> 6)] = se;
  __syncthreads();
  se = sred[4] + sred[5] + sred[6] + sred[7];
  const float inv = 1.f / se;
  #pragma unroll
  for (int i = 0; i < 8; ++i) attn[b * S_N + i * 256 + tid] = l[i] * inv;
}

// ------- K3: context[b][e] = sum_s w[b][s] * enc[b][s][e] -------------------
__global__ __launch_bounds__(512) void k_context(const float* __restrict__ enc,
                                                 const float* __restrict__ attn,
                                                 float* __restrict__ ctx) {
  const int blk = blockIdx.x;
  const int b = blk >> 2, eq = blk & 3;
  const int tid = threadIdx.x;
  const int te = tid & 31, sg = tid >> 5;   // 16 s-groups of 128 rows
  const int e0 = eq * 128 + te * 4;
  const float* ep = enc + (size_t)b * S_N * E_N + e0;
  const float* wp = attn + b * S_N;
  f32x4 acc = {0.f, 0.f, 0.f, 0.f};
  const int s0 = sg * 128;
  #pragma unroll 4
  for (int s = s0; s < s0 + 128; ++s) {
    const float w = wp[s];
    const f32x4 ev = *(const f32x4*)(ep + (size_t)s * E_N);
    acc += w * ev;
  }
  __shared__ f32x4 red[16][32];
  red[sg][te] = acc;
  __syncthreads();
  if (sg == 0) {
    f32x4 t = red[0][te];
    #pragma unroll
    for (int g = 1; g < 16; ++g) t += red[g][te];
    *(f32x4*)(ctx + (size_t)b * E_N + e0) = t;
  }
}

// ------- launch -------------------------------------------------------------
extern "C" void kernel_launch(void* const* d_in, const int* in_sizes, int n_in,
                              void* d_out, int out_size, void* d_ws, size_t ws_size,
                              hipStream_t stream) {
  const float* enc = (const float*)d_in[0];
  const float* dh  = (const float*)d_in[1];
  const float* We  = (const float*)d_in[2];
  const float* Wd  = (const float*)d_in[3];
  const float* v   = (const float*)d_in[4];

  float* out_ctx  = (float*)d_out;
  float* out_attn = out_ctx + B_N * E_N;

  float* sp   = (float*)d_ws;                         // 2 x 131072 f32 partials
  float* decp = sp + 2 * B_N * S_N;                   // 32768 f32
  unsigned short* Wp = (unsigned short*)(decp + B_N * A_N);  // 262144 bf16 packed

  k_pack   <<<128, 256, 0, stream>>>(We, Wp);
  k_decproj<<<B_N, 256, 0, stream>>>(dh, Wd, decp);
  k_scores <<<(B_N * S_N) / 64 * 2, 256, 0, stream>>>(enc, Wp, decp, v, sp);
  k_softmax<<<B_N, 256, 0, stream>>>(sp, out_attn);
  k_context<<<B_N * 4, 512, 0, stream>>>(enc, out_attn, out_ctx);
}

// Round 6
// 193.380 us; speedup vs baseline: 1.9918x; 1.9918x over previous
//
#include <hip/hip_runtime.h>
#include <hip/hip_bf16.h>

#define B_N 64
#define S_N 2048
#define E_N 512
#define A_N 512

typedef __bf16 bf16x8 __attribute__((ext_vector_type(8)));
typedef float  f32x4  __attribute__((ext_vector_type(4)));

__device__ __forceinline__ unsigned int f2bfu(float f) {
  return (unsigned int)__builtin_bit_cast(unsigned short, (__bf16)f);
}

// ------- K0a: pack W_enc fp32 [A][E] -> bf16 in MFMA-fragment order --------
// chunk pk = (c*16 + k32)*64 + l  (16 bytes each), l = q*16+ln
// holds W[a = c*16+ln][k = k32*32 + q*8 + j], j=0..7
__global__ __launch_bounds__(256) void k_pack(const float* __restrict__ W,
                                              unsigned short* __restrict__ Wp) {
  const int pk = blockIdx.x * 256 + threadIdx.x;      // [0, 32768)
  const int l = pk & 63, k32 = (pk >> 6) & 15, c = pk >> 10;
  const int ln = l & 15, q = l >> 4;
  const int a = c * 16 + ln, k = k32 * 32 + q * 8;
  const float* src = W + (size_t)a * E_N + k;
  const float4 u = *(const float4*)src;
  const float4 w = *(const float4*)(src + 4);
  uint4 o;
  o.x = f2bfu(u.x) | (f2bfu(u.y) << 16);
  o.y = f2bfu(u.z) | (f2bfu(u.w) << 16);
  o.z = f2bfu(w.x) | (f2bfu(w.y) << 16);
  o.w = f2bfu(w.z) | (f2bfu(w.w) << 16);
  *(uint4*)(Wp + (size_t)pk * 8) = o;
}

// ------- K0b: dec_proj[b][a] = dot(dec_hidden[b], W_dec[a]) ----------------
__global__ __launch_bounds__(256) void k_decproj(const float* __restrict__ dh,
                                                 const float* __restrict__ Wd,
                                                 float* __restrict__ decp) {
  const int b = blockIdx.x, tid = threadIdx.x;
  __shared__ float h[E_N];
  h[tid] = dh[b * E_N + tid];
  h[tid + 256] = dh[b * E_N + 256 + tid];
  __syncthreads();
  for (int a = tid; a < A_N; a += 256) {
    const float* wr = Wd + (size_t)a * E_N;
    float s = 0.f;
    #pragma unroll 8
    for (int e = 0; e < E_N; e += 4) {
      const float4 w4 = *(const float4*)(wr + e);
      s += w4.x * h[e] + w4.y * h[e + 1] + w4.z * h[e + 2] + w4.w * h[e + 3];
    }
    decp[b * A_N + a] = s;
  }
}

// ------- K1: scores = sum_a v[a]*tanh(enc@We^T + decp) ---------------------
// R4 structure (64 rows x full K in LDS, 2 barriers, B from L2-resident
// packed W) but with COMPACT CODE: rolled staging + rolled 16-step K-loop
// (~60-instr body) to fit L1I. 512 thr = 8 waves; wave wv owns 64 cols.
#define LDS_A   65536                 // 64 rows x 1024 B
#define RED_OFF LDS_A
#define LDS_TOT (LDS_A + 8 * 64 * 4)

__device__ __forceinline__ int a_off(int r, int kb) {
  return r * 1024 + (kb ^ ((r & 7) << 4));
}

__global__ __launch_bounds__(512, 4) void k_scores(
    const float* __restrict__ enc, const unsigned short* __restrict__ Wp,
    const float* __restrict__ decp, const float* __restrict__ vvec,
    float* __restrict__ scores) {
  __shared__ __align__(16) unsigned char lds[LDS_TOT];
  const int tid = threadIdx.x;
  const int lane = tid & 63, wv = tid >> 6, q = lane >> 4, ln = lane & 15;
  const int row0 = blockIdx.x * 64;
  const int b = row0 >> 11;
  const bf16x8* __restrict__ Wp16 = (const bf16x8*)Wp;

  // hoisted epilogue constants (block stays within one b)
  float vv[4], dp[4];
  #pragma unroll
  for (int nt = 0; nt < 4; ++nt) {
    const int a = wv * 64 + nt * 16 + ln;
    vv[nt] = vvec[a];
    dp[nt] = decp[b * A_N + a];
  }

  // ---- stage (rolled): wave wv owns rows row0+wv*8..+8, full 2KB per row;
  // lane covers 8 consecutive floats (32B) of each row.
  {
    const float* srow = enc + (size_t)(row0 + wv * 8) * E_N + lane * 8;
    #pragma unroll 2
    for (int r8 = 0; r8 < 8; ++r8) {
      const float4 u = *(const float4*)(srow + (size_t)r8 * E_N);
      const float4 w = *(const float4*)(srow + (size_t)r8 * E_N + 4);
      uint4 o;
      o.x = f2bfu(u.x) | (f2bfu(u.y) << 16);
      o.y = f2bfu(u.z) | (f2bfu(u.w) << 16);
      o.z = f2bfu(w.x) | (f2bfu(w.y) << 16);
      o.w = f2bfu(w.z) | (f2bfu(w.w) << 16);
      *(uint4*)(lds + a_off(wv * 8 + r8, lane * 16)) = o;
    }
  }
  __syncthreads();

  // ---- compute: rolled 16 K-steps (K=32 each), zero barriers ----
  f32x4 acc[4][4] = {};
  #pragma unroll 1
  for (int kss = 0; kss < 16; ++kss) {
    bf16x8 bfr[4], afr[4];
    #pragma unroll
    for (int nt = 0; nt < 4; ++nt)
      bfr[nt] = Wp16[(size_t)((wv * 4 + nt) * 16 + kss) * 64 + lane];
    #pragma unroll
    for (int mt = 0; mt < 4; ++mt)
      afr[mt] = *(const bf16x8*)(lds + a_off(mt * 16 + ln, kss * 64 + q * 16));
    #pragma unroll
    for (int mt = 0; mt < 4; ++mt)
      #pragma unroll
      for (int nt = 0; nt < 4; ++nt)
        acc[mt][nt] = __builtin_amdgcn_mfma_f32_16x16x32_bf16(
            afr[mt], bfr[nt], acc[mt][nt], 0, 0, 0);
  }

  // ---- epilogue: tanh(x + decp) * v, reduce over a ----
  float part[4][4] = {};
  #pragma unroll
  for (int mt = 0; mt < 4; ++mt)
    #pragma unroll
    for (int nt = 0; nt < 4; ++nt)
      #pragma unroll
      for (int r = 0; r < 4; ++r) {
        float x = acc[mt][nt][r] + dp[nt];
        x = fminf(9.f, fmaxf(-9.f, x));
        const float ex = __expf(2.f * x);
        part[mt][r] = fmaf(__fdividef(ex - 1.f, ex + 1.f), vv[nt], part[mt][r]);
      }
  float* red = (float*)(lds + RED_OFF);
  #pragma unroll
  for (int mt = 0; mt < 4; ++mt)
    #pragma unroll
    for (int r = 0; r < 4; ++r) {
      float s = part[mt][r];
      s += __shfl_xor(s, 1);
      s += __shfl_xor(s, 2);
      s += __shfl_xor(s, 4);
      s += __shfl_xor(s, 8);
      if (ln == 0) red[wv * 64 + mt * 16 + q * 4 + r] = s;
    }
  __syncthreads();
  if (tid < 64) {
    float s = 0.f;
    #pragma unroll
    for (int w8 = 0; w8 < 8; ++w8) s += red[w8 * 64 + tid];
    scores[row0 + tid] = s;
  }
}

// ------- K2: softmax over S per b -------------------------------------------
__global__ __launch_bounds__(256) void k_softmax(const float* __restrict__ scores,
                                                 float* __restrict__ attn) {
  const int b = blockIdx.x, tid = threadIdx.x;
  float l[8];
  float mx = -3.4e38f;
  #pragma unroll
  for (int i = 0; i < 8; ++i) {
    l[i] = scores[b * S_N + i * 256 + tid];
    mx = fmaxf(mx, l[i]);
  }
  #pragma unroll
  for (int m = 1; m < 64; m <<= 1) mx = fmaxf(mx, __shfl_xor(mx, m));
  __shared__ float sred[8];
  if ((tid & 63) == 0) sred[tid >> 6] = mx;
  __syncthreads();
  mx = fmaxf(fmaxf(sred[0], sred[1]), fmaxf(sred[2], sred[3]));
  float se = 0.f;
  #pragma unroll
  for (int i = 0; i < 8; ++i) { l[i] = __expf(l[i] - mx); se += l[i]; }
  #pragma unroll
  for (int m = 1; m < 64; m <<= 1) se += __shfl_xor(se, m);
  if ((tid & 63) == 0) sred[4 + (tid >> 6)] = se;
  __syncthreads();
  se = sred[4] + sred[5] + sred[6] + sred[7];
  const float inv = 1.f / se;
  #pragma unroll
  for (int i = 0; i < 8; ++i) attn[b * S_N + i * 256 + tid] = l[i] * inv;
}

// ------- K3: context[b][e] = sum_s w[b][s] * enc[b][s][e] -------------------
__global__ __launch_bounds__(512) void k_context(const float* __restrict__ enc,
                                                 const float* __restrict__ attn,
                                                 float* __restrict__ ctx) {
  const int blk = blockIdx.x;
  const int b = blk >> 2, eq = blk & 3;
  const int tid = threadIdx.x;
  const int te = tid & 31, sg = tid >> 5;   // 16 s-groups of 128 rows
  const int e0 = eq * 128 + te * 4;
  const float* ep = enc + (size_t)b * S_N * E_N + e0;
  const float* wp = attn + b * S_N;
  f32x4 acc = {0.f, 0.f, 0.f, 0.f};
  const int s0 = sg * 128;
  #pragma unroll 4
  for (int s = s0; s < s0 + 128; ++s) {
    const float w = wp[s];
    const f32x4 ev = *(const f32x4*)(ep + (size_t)s * E_N);
    acc += w * ev;
  }
  __shared__ f32x4 red[16][32];
  red[sg][te] = acc;
  __syncthreads();
  if (sg == 0) {
    f32x4 t = red[0][te];
    #pragma unroll
    for (int g = 1; g < 16; ++g) t += red[g][te];
    *(f32x4*)(ctx + (size_t)b * E_N + e0) = t;
  }
}

// ------- launch -------------------------------------------------------------
extern "C" void kernel_launch(void* const* d_in, const int* in_sizes, int n_in,
                              void* d_out, int out_size, void* d_ws, size_t ws_size,
                              hipStream_t stream) {
  const float* enc = (const float*)d_in[0];
  const float* dh  = (const float*)d_in[1];
  const float* We  = (const float*)d_in[2];
  const float* Wd  = (const float*)d_in[3];
  const float* v   = (const float*)d_in[4];

  float* out_ctx  = (float*)d_out;
  float* out_attn = out_ctx + B_N * E_N;

  float* scores = (float*)d_ws;                       // 131072 f32
  float* decp   = scores + B_N * S_N;                 // 32768 f32
  unsigned short* Wp = (unsigned short*)(decp + B_N * A_N);  // 262144 bf16 packed

  k_pack   <<<128, 256, 0, stream>>>(We, Wp);
  k_decproj<<<B_N, 256, 0, stream>>>(dh, Wd, decp);
  k_scores <<<(B_N * S_N) / 64, 512, 0, stream>>>(enc, Wp, decp, v, scores);
  k_softmax<<<B_N, 256, 0, stream>>>(scores, out_attn);
  k_context<<<B_N * 4, 512, 0, stream>>>(enc, out_attn, out_ctx);
}